// Round 8
// baseline (1175.560 us; speedup 1.0000x reference)
//
#include <hip/hip_runtime.h>
#include <stdint.h>

typedef _Float16 f16;
typedef _Float16 f16x8 __attribute__((ext_vector_type(8)));
typedef float f32x4 __attribute__((ext_vector_type(4)));
typedef float f32x16 __attribute__((ext_vector_type(16)));

#define B_ROWS 32768
#define DIM 512
#define NP 8
#define NK 10

typedef __attribute__((address_space(3))) unsigned int lds_u32;
typedef __attribute__((address_space(1))) const unsigned int gbl_u32;

__device__ __forceinline__ void gload_lds16(const void* g, void* l) {
  __builtin_amdgcn_global_load_lds((gbl_u32*)(uintptr_t)g, (lds_u32*)(uintptr_t)l, 16, 0, 0);
}

// ---------------- prep: combined split (X hi/lo, W1 hi/lo, W2 hi) ----------------

__global__ void prep_split(const float* __restrict__ X, f16* __restrict__ Xh,
                           f16* __restrict__ Xl, const float* __restrict__ W1,
                           f16* __restrict__ W1h, f16* __restrict__ W1l,
                           const float* __restrict__ W2, f16* __restrict__ W2h) {
  int bid = blockIdx.x, tid = threadIdx.x;
  if (bid < 2048) {
    for (int i = bid * 256 + tid; i < 16777216; i += 2048 * 256) {
      float v = X[i];
      f16 h = (f16)v;
      Xh[i] = h;
      Xl[i] = (f16)(v - (float)h);
    }
  } else if (bid < 2560) {
    for (int i = (bid - 2048) * 256 + tid; i < 2097152; i += 512 * 256) {
      float v = W1[i];
      f16 h = (f16)v;
      W1h[i] = h;
      W1l[i] = (f16)(v - (float)h);
    }
  } else {
    for (int i = (bid - 2560) * 256 + tid; i < 2097152; i += 512 * 256) {
      W2h[i] = (f16)W2[i];
    }
  }
}

// ---------------- enorm2: E2 rows + Emean rows + E2m ----------------

__global__ void enorm2(const float* __restrict__ E, float* __restrict__ Emean,
                       float* __restrict__ E2, float* __restrict__ E2m) {
  int bid = blockIdx.x;  // 0..79 -> E2[p*10+k]; 80..89 -> Emean row + E2m[k]
  int lane = threadIdx.x;  // block = 64
  if (bid < 80) {
    const float* src = E + (size_t)bid * DIM;
    float s = 0.f;
    for (int i = lane; i < DIM; i += 64) {
      float v = src[i];
      s = fmaf(v, v, s);
    }
#pragma unroll
    for (int m = 1; m < 64; m <<= 1) s += __shfl_xor(s, m, 64);
    if (lane == 0) E2[bid] = s;
  } else {
    int k = bid - 80;
    float acc = 0.f;
    for (int i = lane; i < DIM; i += 64) {
      float s = 0.f;
#pragma unroll
      for (int p = 0; p < NP; ++p) s += E[p * NK * DIM + k * DIM + i];
      s *= 0.125f;
      Emean[k * DIM + i] = s;
      acc = fmaf(s, s, acc);
    }
#pragma unroll
    for (int m = 1; m < 64; m <<= 1) acc += __shfl_xor(acc, m, 64);
    if (lane == 0) E2m[k] = acc;
  }
}

// ---------------- etilde + Eimg pack: Et=W2^T E (fp16-split padded image), c=b2·E ----------------

__global__ __launch_bounds__(512) void etilde_kernel(const float* __restrict__ W2,
                                                     const float* __restrict__ b2,
                                                     const float* __restrict__ E,
                                                     f16* __restrict__ EimgH,
                                                     f16* __restrict__ EimgL,
                                                     float* __restrict__ c_) {
  const int p = blockIdx.x / NK, k = blockIdx.x % NK;
  const int h = threadIdx.x;  // 512 threads
  __shared__ float Er[512];
  __shared__ float red[8];
  Er[h] = E[((size_t)p * NK + k) * DIM + h];
  __syncthreads();
  const float* Wp = W2 + (size_t)p * DIM * DIM;
  float s = 0.f;
#pragma unroll 8
  for (int d = 0; d < DIM; ++d) s = fmaf(Wp[(size_t)d * DIM + h], Er[d], s);
  int ei = p * 8320 + k * 520 + h;
  f16 hi = (f16)s;
  EimgH[ei] = hi;
  EimgL[ei] = (f16)(s - (float)hi);
  if (h < 8) {
    int pi = p * 8320 + k * 520 + 512 + h;
    EimgH[pi] = (f16)0.f;
    EimgL[pi] = (f16)0.f;
  }
  if (k == 0) {
    for (int j = h; j < 6 * 520; j += 512) {
      int pi = p * 8320 + 10 * 520 + j;
      EimgH[pi] = (f16)0.f;
      EimgL[pi] = (f16)0.f;
    }
  }
  float t = b2[p * DIM + h] * Er[h];
#pragma unroll
  for (int m = 1; m < 64; m <<= 1) t += __shfl_xor(t, m, 64);
  if ((h & 63) == 0) red[h >> 6] = t;
  __syncthreads();
  if (h == 0) {
    float cc = 0.f;
#pragma unroll
    for (int i = 0; i < 8; ++i) cc += red[i];
    c_[p * NK + k] = cc;
  }
}

// ---------------- m97-structure 128x128 GEMM-BT, 32x32x16 MFMA inner loop ----------------
// C[m][n] = sum_k A[m][k]*B[n][k].
// NPROD=3: split-fp16 (Ah·Bh, Ah·Bl, Al·Bh k-major). NPROD=1: Ah·Bh only.
// GRP: L2 banding — XCD chunk walks GRP-bm bands bm-fastest.
// A/B frag: row = lane&31, k = (lane>>5)*8.  C/D: col=lane&31,
// row = (reg&3)+8*(reg>>2)+4*(lane>>5)  [guide m74/m101].
// EPI 0: relu(acc+bias) -> Oh/Ol f16.  EPI 1: row partials of sum(z^2) -> part2.

template <int EPI, int NBN, int NPROD, int GRP>
__global__ __launch_bounds__(256) void gemmA(
    const f16* __restrict__ Ah_, const f16* __restrict__ Al_, int lda, int apitch,
    const f16* __restrict__ Bh_, const f16* __restrict__ Bl_, int bpitch,
    const float* __restrict__ bias_, int bias_pitch,
    f16* __restrict__ Oh, f16* __restrict__ Ol, int ldo,
    float* __restrict__ part2) {
  __shared__ f16 smem[32768];  // 64 KB: 2 buf x [A 8192 | B 8192]
  const int tid = threadIdx.x;
  const int lane = tid & 63;
  const int wave = tid >> 6;
  const int wr = wave >> 1, wc = wave & 1;
  const int p = blockIdx.z;

  const int q8 = gridDim.x >> 3;
  const int bid = blockIdx.x;
  const int swz = (bid & 7) * q8 + (bid >> 3);
  const int band = swz / (GRP * NBN);
  const int r_ = swz % (GRP * NBN);
  const int bm = band * GRP + (r_ % GRP);
  const int bn = r_ / GRP;
  const int m0 = bm * 128, n0 = bn * 128;

  const f16* Ahp = Ah_ + (size_t)p * apitch;
  const f16* Alp = Al_ + (size_t)p * apitch;
  const f16* Bhp = Bh_ + (size_t)p * bpitch;
  const f16* Blp = Bl_ + (size_t)p * bpitch;

  const int NT = (NPROD == 3) ? 24 : 8;

  f32x16 acc[2][2] = {};

  auto stage = [&](int buf, int t) {
    const f16* As;
    const f16* Bs;
    int k0;
    if (NPROD == 3) {
      int pr = t % 3;  // 0:(Ah,Bh) 1:(Ah,Bl) 2:(Al,Bh)
      As = (pr == 2) ? Alp : Ahp;
      Bs = (pr == 1) ? Blp : Bhp;
      k0 = (t / 3) * 64;
    } else {
      As = Ahp;
      Bs = Bhp;
      k0 = t * 64;
    }
    f16* sA = smem + buf * 16384;
    f16* sB = sA + 8192;
#pragma unroll
    for (int j = 0; j < 4; ++j) {
      int r = j * 32 + (tid >> 3);
      int c = ((tid & 7) ^ (r & 7)) * 8;  // pre-swizzled source col
      gload_lds16(As + (size_t)(m0 + r) * lda + k0 + c, sA + j * 2048 + tid * 8);
      gload_lds16(Bs + (size_t)(n0 + r) * 512 + k0 + c, sB + j * 2048 + tid * 8);
    }
  };

  stage(0, 0);
  __syncthreads();

  const int l31 = lane & 31, lh = lane >> 5;

  for (int s = 0; s < NT; ++s) {
    int nx = s + 1;
    if (nx < NT) stage(nx & 1, nx);
    const char* sA = (const char*)(smem + (s & 1) * 16384);
    const char* sB = sA + 16384;  // bytes
    f16x8 af[2][4], bf[2][4];
#pragma unroll
    for (int rb = 0; rb < 2; ++rb) {
      int ra = wr * 64 + rb * 32 + l31;
#pragma unroll
      for (int ks = 0; ks < 4; ++ks) {
        int cb = ks * 32 + lh * 16;
        af[rb][ks] = *(const f16x8*)(sA + ra * 128 + (cb ^ ((ra & 7) << 4)));
      }
    }
#pragma unroll
    for (int cb2 = 0; cb2 < 2; ++cb2) {
      int rbc = wc * 64 + cb2 * 32 + l31;
#pragma unroll
      for (int ks = 0; ks < 4; ++ks) {
        int cb = ks * 32 + lh * 16;
        bf[cb2][ks] = *(const f16x8*)(sB + rbc * 128 + (cb ^ ((rbc & 7) << 4)));
      }
    }
#pragma unroll
    for (int rb = 0; rb < 2; ++rb)
#pragma unroll
      for (int cb2 = 0; cb2 < 2; ++cb2)
#pragma unroll
        for (int ks = 0; ks < 4; ++ks)
          acc[rb][cb2] = __builtin_amdgcn_mfma_f32_32x32x16_f16(af[rb][ks], bf[cb2][ks], acc[rb][cb2], 0, 0, 0);
    __syncthreads();
  }

  if (EPI == 0) {
#pragma unroll
    for (int cb2 = 0; cb2 < 2; ++cb2) {
      int cg = n0 + wc * 64 + cb2 * 32 + l31;
      float bv = bias_[cg];
#pragma unroll
      for (int rb = 0; rb < 2; ++rb) {
#pragma unroll
        for (int reg = 0; reg < 16; ++reg) {
          int row = m0 + wr * 64 + rb * 32 + (reg & 3) + 8 * (reg >> 2) + 4 * lh;
          float z = acc[rb][cb2][reg] + bv;
          z = fmaxf(z, 0.f);
          f16 h = (f16)z;
          size_t off = (size_t)row * ldo + cg;
          Oh[off] = h;
          Ol[off] = (f16)(z - (float)h);
        }
      }
    }
  } else {
    const float* bp = bias_ + (size_t)p * bias_pitch;
    float bv[2];
#pragma unroll
    for (int cb2 = 0; cb2 < 2; ++cb2) bv[cb2] = bp[n0 + wc * 64 + cb2 * 32 + l31];
    const int ch = bn * 2 + wc;  // 0..7 (NBN=4)
    float* pb = part2 + (size_t)(p * 8 + ch) * B_ROWS;
#pragma unroll
    for (int rb = 0; rb < 2; ++rb) {
#pragma unroll
      for (int reg = 0; reg < 16; ++reg) {
        float s = 0.f;
#pragma unroll
        for (int cb2 = 0; cb2 < 2; ++cb2) {
          float z = acc[rb][cb2][reg] + bv[cb2];
          s = fmaf(z, z, s);
        }
        s += __shfl_xor(s, 1, 64);
        s += __shfl_xor(s, 2, 64);
        s += __shfl_xor(s, 4, 64);
        s += __shfl_xor(s, 8, 64);
        s += __shfl_xor(s, 16, 64);
        if (l31 == 0)
          pb[m0 + wr * 64 + rb * 32 + (reg & 3) + 8 * (reg >> 2) + 4 * lh] = s;
      }
    }
  }
}

// ---------------- dots via skinny MFMA: g[p][b][k] = h[b]·Et[p][k] + c[p][k] ----------------
// writes directly into the dist output region ([p][b][k] layout)

__global__ __launch_bounds__(256) void dots_mfma(const f16* __restrict__ Hh,
                                                 const f16* __restrict__ Hl,
                                                 const f16* __restrict__ EimgH,
                                                 const f16* __restrict__ EimgL,
                                                 const float* __restrict__ c_,
                                                 float* __restrict__ gout) {
  __shared__ f16 sH[8192];
  __shared__ f16 sL[8192];
  __shared__ f16 sEh[16 * 520];
  __shared__ f16 sEl[16 * 520];
  const int tid = threadIdx.x;
  const int lane = tid & 63, wave = tid >> 6;
  const int p = blockIdx.y;
  const int r0 = blockIdx.x * 128;
  {
    const uint32_t* ih = (const uint32_t*)(EimgH + (size_t)p * 16 * 520);
    const uint32_t* il = (const uint32_t*)(EimgL + (size_t)p * 16 * 520);
    uint32_t* oh = (uint32_t*)sEh;
    uint32_t* ol = (uint32_t*)sEl;
    for (int i = tid; i < 16 * 520 / 2; i += 256) {
      oh[i] = ih[i];
      ol[i] = il[i];
    }
  }
  const int gq = lane >> 4, rl = lane & 15;
  f32x4 acc[2] = {};
  for (int t = 0; t < 8; ++t) {
    __syncthreads();
#pragma unroll
    for (int j = 0; j < 4; ++j) {
      int r = j * 32 + (tid >> 3);
      int c = ((tid & 7) ^ (r & 7)) * 8;
      gload_lds16(Hh + (size_t)(r0 + r) * 4096 + p * DIM + t * 64 + c, sH + j * 2048 + tid * 8);
      gload_lds16(Hl + (size_t)(r0 + r) * 4096 + p * DIM + t * 64 + c, sL + j * 2048 + tid * 8);
    }
    __syncthreads();
    const char* bh = (const char*)sH;
    const char* bl = (const char*)sL;
    const char* eh = (const char*)sEh;
    const char* el = (const char*)sEl;
    f16x8 ah[2][2], al[2][2], beh[2], bel[2];
#pragma unroll
    for (int mf = 0; mf < 2; ++mf) {
      int ra = wave * 32 + mf * 16 + rl;
#pragma unroll
      for (int kk = 0; kk < 2; ++kk) {
        int cb = kk * 64 + gq * 16;
        ah[mf][kk] = *(const f16x8*)(bh + ra * 128 + (cb ^ ((ra & 7) << 4)));
        al[mf][kk] = *(const f16x8*)(bl + ra * 128 + (cb ^ ((ra & 7) << 4)));
      }
    }
#pragma unroll
    for (int kk = 0; kk < 2; ++kk) {
      int cb = t * 128 + kk * 64 + gq * 16;
      beh[kk] = *(const f16x8*)(eh + rl * 1040 + cb);
      bel[kk] = *(const f16x8*)(el + rl * 1040 + cb);
    }
#pragma unroll
    for (int mf = 0; mf < 2; ++mf)
#pragma unroll
      for (int kk = 0; kk < 2; ++kk) {
        acc[mf] = __builtin_amdgcn_mfma_f32_16x16x32_f16(ah[mf][kk], beh[kk], acc[mf], 0, 0, 0);
        acc[mf] = __builtin_amdgcn_mfma_f32_16x16x32_f16(ah[mf][kk], bel[kk], acc[mf], 0, 0, 0);
        acc[mf] = __builtin_amdgcn_mfma_f32_16x16x32_f16(al[mf][kk], beh[kk], acc[mf], 0, 0, 0);
      }
  }
  if (rl < NK) {
    float cv = c_[p * NK + rl];
#pragma unroll
    for (int mf = 0; mf < 2; ++mf)
#pragma unroll
      for (int r = 0; r < 4; ++r) {
        int row = r0 + wave * 32 + mf * 16 + gq * 4 + r;
        gout[((size_t)p * B_ROWS + row) * NK + rl] = acc[mf][r] + cv;
      }
  }
}

// ---------------- final: dist in-place, argmin, vq_z, loss, changed, avz (fused bcast) ----------------
// avz hole (k==8 && b<4096) holds part2 scratch; filled by bcast_rest afterwards.

__global__ __launch_bounds__(256) void final_kernel(
    const float* __restrict__ X, const float* __restrict__ part2,
    float* __restrict__ gdist, const float* __restrict__ E2,
    const float* __restrict__ Emean, const float* __restrict__ E2m,
    const int* __restrict__ label, float* __restrict__ vq_z,
    float* __restrict__ avz, float* __restrict__ loss, float* __restrict__ changed) {
  __shared__ float Em[NK * DIM];
  __shared__ float e2s[NK];
  const int tid = threadIdx.x;
  for (int i = tid; i < NK * DIM; i += 256) Em[i] = Emean[i];
  if (tid < NK) e2s[tid] = E2m[tid];
  __syncthreads();

  const int b0 = blockIdx.x * 16;
  {
    const float4* Em4 = (const float4*)Em;
    float4* avz4 = (float4*)avz;
    if (blockIdx.x < 256) {
      for (int it = 0; it < 80; ++it) {
        int idx = it * 256 + tid;
        int d4 = idx & 127, row = (idx >> 7) & 15, k = idx >> 11;
        if (k == 8) continue;  // hole: part2 scratch
        avz4[(((size_t)k * B_ROWS + b0 + row) << 7) + d4] = Em4[k * 128 + d4];
      }
    } else {
      for (int it = 0; it < 80; ++it) {
        int idx = it * 256 + tid;
        int d4 = idx & 127, row = (idx >> 7) & 15, k = idx >> 11;
        avz4[(((size_t)k * B_ROWS + b0 + row) << 7) + d4] = Em4[k * 128 + d4];
      }
    }
  }

  const int lane = tid & 63, wave = tid >> 6;
  const int pl = lane & 7, kh = lane >> 3;
  for (int rr = 0; rr < 4; ++rr) {
    int b = b0 + wave * 4 + rr;
    float zq = part2[(size_t)(pl * 8 + kh) * B_ROWS + b];
    zq += __shfl_xor(zq, 8, 64);
    zq += __shfl_xor(zq, 16, 64);
    zq += __shfl_xor(zq, 32, 64);
    float g0 = gdist[((size_t)pl * B_ROWS + b) * NK + kh];
    float g1 = (lane < 16) ? gdist[((size_t)pl * B_ROWS + b) * NK + 8 + kh] : 0.f;
    float dv0 = zq + E2[pl * NK + kh] - 2.f * g0;
    float dv1 = zq + E2[pl * NK + 8 + kh] - 2.f * g1;
    gdist[((size_t)pl * B_ROWS + b) * NK + kh] = dv0;
    if (lane < 16) gdist[((size_t)pl * B_ROWS + b) * NK + 8 + kh] = dv1;
    float v0 = dv0, v1 = (lane < 16) ? dv1 : 0.f;
#pragma unroll
    for (int m = 1; m < 8; m <<= 1) {
      v0 += __shfl_xor(v0, m, 64);
      v1 += __shfl_xor(v1, m, 64);
    }
    float a[NK];
#pragma unroll
    for (int k = 0; k < 8; ++k) a[k] = __shfl(v0, k * 8, 64);
    a[8] = __shfl(v1, 0, 64);
    a[9] = __shfl(v1, 8, 64);
    int idx = 0;
    float mn = a[0];
#pragma unroll
    for (int k = 1; k < NK; ++k) {
      if (a[k] < mn) { mn = a[k]; idx = k; }
    }
    const float* xr = X + (size_t)b * DIM;
    float sx = 0.f, dx[NK] = {};
#pragma unroll
    for (int j = 0; j < 8; ++j) {
      float x = xr[j * 64 + lane];
      sx = fmaf(x, x, sx);
#pragma unroll
      for (int k = 0; k < NK; ++k) dx[k] = fmaf(x, Em[k * DIM + j * 64 + lane], dx[k]);
    }
#pragma unroll
    for (int m = 1; m < 64; m <<= 1) {
      sx += __shfl_xor(sx, m, 64);
#pragma unroll
      for (int k = 0; k < NK; ++k) dx[k] += __shfl_xor(dx[k], m, 64);
    }
    if (lane == 0) {
#pragma unroll
      for (int k = 0; k < NK; ++k)
        loss[(size_t)k * B_ROWS + b] = 1.25f * (sx - 2.f * dx[k] + e2s[k]);
    }
    int lab = label[b];
#pragma unroll
    for (int j = 0; j < 8; ++j) {
      int c = j * 64 + lane;
      vq_z[(size_t)b * DIM + c] = Em[idx * DIM + c];
      changed[(size_t)b * DIM + c] = Em[lab * DIM + c];
    }
  }
}

// ---------------- bcast_rest: fill the avz hole (k=8, b<4096) ----------------

__global__ void bcast_rest(const float* __restrict__ Emean, float4* __restrict__ avz4) {
  const float4* Em4 = (const float4*)Emean;
  int tid = blockIdx.x * 256 + threadIdx.x;
  for (int it = 0; it < 32; ++it) {
    int idx = tid + it * 16384;  // 0 .. 524287
    int b = idx >> 7, d4 = idx & 127;
    avz4[((size_t)(8 * B_ROWS + b) << 7) + d4] = Em4[8 * 128 + d4];
  }
}

// ---------------- launch ----------------

extern "C" void kernel_launch(void* const* d_in, const int* in_sizes, int n_in,
                              void* d_out, int out_size, void* d_ws, size_t ws_size,
                              hipStream_t stream) {
  const float* X = (const float*)d_in[0];
  const float* W1 = (const float*)d_in[1];
  const float* b1 = (const float*)d_in[2];
  const float* W2 = (const float*)d_in[3];
  const float* b2 = (const float*)d_in[4];
  const float* E = (const float*)d_in[5];
  const int* lab = (const int*)d_in[6];
  float* out = (float*)d_out;

  // output layout (flat f32, return order)
  float* vq_z = out;                               // 16,777,216
  float* dist = out + 16777216;                    // 2,621,440
  float* avz = out + 16777216 + 2621440;           // 167,772,160
  float* loss = avz + 167772160;                   // 327,680
  float* chg = loss + 327680;                      // 16,777,216

  // scratch carved from output regions:
  f16* Xh = (f16*)vq_z;                       // 33.5 MB (consumed by GEMM1)
  f16* Xl = Xh + 16777216;
  f16* Hh = (f16*)avz;                        // 268 MB
  f16* Hl = Hh + 134217728;                   // 268 MB (ends at avz float 134217728)
  float* part2 = avz + 134217728;             // 8 MB = avz rows (k=8, b<4096) — the hole

  // small ws allocations (~13 MB)
  char* w = (char*)d_ws;
  f16* W1h = (f16*)w; w += 4194304;
  f16* W1l = (f16*)w; w += 4194304;
  f16* W2h = (f16*)w; w += 4194304;
  float* Emean = (float*)w; w += NK * DIM * 4;
  float* E2 = (float*)w; w += 512;
  float* E2m = (float*)w; w += 256;
  float* c_ = (float*)w; w += 512;
  f16* EimgH = (f16*)w; w += NP * 16 * 520 * 2;   // 133 KB
  f16* EimgL = (f16*)w; w += NP * 16 * 520 * 2;

  prep_split<<<3072, 256, 0, stream>>>(X, Xh, Xl, W1, W1h, W1l, W2, W2h);
  enorm2<<<90, 64, 0, stream>>>(E, Emean, E2, E2m);
  etilde_kernel<<<80, 512, 0, stream>>>(W2, b2, E, EimgH, EimgL, c_);

  // GEMM1: [32768x512] x [4096x512]^T -> Hh/Hl (relu + f16 split), 3 products
  gemmA<0, 32, 3, 8><<<dim3(8192, 1, 1), 256, 0, stream>>>(
      Xh, Xl, 512, 0, W1h, W1l, 0, b1, 0, Hh, Hl, 4096, nullptr);
  // GEMM2: per-p [32768x512] x [512x512]^T, 1 product -> zsq partials
  gemmA<1, 4, 1, 1><<<dim3(1024, 1, NP), 256, 0, stream>>>(
      Hh, Hh, 4096, 512, W2h, W2h, 262144, b2, 512, nullptr, nullptr, 0, part2);

  // dots: g -> dist region (in-place consumed by final)
  dots_mfma<<<dim3(256, NP), 256, 0, stream>>>(Hh, Hl, EimgH, EimgL, c_, dist);
  final_kernel<<<2048, 256, 0, stream>>>(X, part2, dist, E2, Emean, E2m, lab,
                                         vq_z, avz, loss, chg);
  bcast_rest<<<64, 256, 0, stream>>>(Emean, (float4*)avz);
}

// Round 9
// 1110.438 us; speedup vs baseline: 1.0586x; 1.0586x over previous
//
#include <hip/hip_runtime.h>
#include <stdint.h>

typedef _Float16 f16;
typedef _Float16 f16x4 __attribute__((ext_vector_type(4)));
typedef _Float16 f16x8 __attribute__((ext_vector_type(8)));
typedef float f32x4 __attribute__((ext_vector_type(4)));

#define B_ROWS 32768
#define DIM 512
#define NP 8
#define NK 10

typedef __attribute__((address_space(3))) unsigned int lds_u32;
typedef __attribute__((address_space(1))) const unsigned int gbl_u32;

__device__ __forceinline__ void gload_lds16(const void* g, void* l) {
  __builtin_amdgcn_global_load_lds((gbl_u32*)(uintptr_t)g, (lds_u32*)(uintptr_t)l, 16, 0, 0);
}

// ---------------- prep: vectorized combined split (X hi/lo, W1 hi/lo, W2 hi) ----------------

__global__ void prep_split(const float4* __restrict__ X4, f16x4* __restrict__ Xh4,
                           f16x4* __restrict__ Xl4, const float4* __restrict__ W14,
                           f16x4* __restrict__ W1h4, f16x4* __restrict__ W1l4,
                           const float4* __restrict__ W24, f16x4* __restrict__ W2h4) {
  int bid = blockIdx.x, tid = threadIdx.x;
  if (bid < 1024) {
    for (int i = bid * 256 + tid; i < 4194304; i += 1024 * 256) {
      float4 v = X4[i];
      f16x4 h = {(f16)v.x, (f16)v.y, (f16)v.z, (f16)v.w};
      f16x4 l = {(f16)(v.x - (float)h[0]), (f16)(v.y - (float)h[1]),
                 (f16)(v.z - (float)h[2]), (f16)(v.w - (float)h[3])};
      Xh4[i] = h;
      Xl4[i] = l;
    }
  } else if (bid < 1152) {
    for (int i = (bid - 1024) * 256 + tid; i < 524288; i += 128 * 256) {
      float4 v = W14[i];
      f16x4 h = {(f16)v.x, (f16)v.y, (f16)v.z, (f16)v.w};
      f16x4 l = {(f16)(v.x - (float)h[0]), (f16)(v.y - (float)h[1]),
                 (f16)(v.z - (float)h[2]), (f16)(v.w - (float)h[3])};
      W1h4[i] = h;
      W1l4[i] = l;
    }
  } else {
    for (int i = (bid - 1152) * 256 + tid; i < 524288; i += 128 * 256) {
      float4 v = W24[i];
      f16x4 h = {(f16)v.x, (f16)v.y, (f16)v.z, (f16)v.w};
      W2h4[i] = h;
    }
  }
}

// ---------------- enorm2: E2 rows + Emean rows + E2m ----------------

__global__ void enorm2(const float* __restrict__ E, float* __restrict__ Emean,
                       float* __restrict__ E2, float* __restrict__ E2m) {
  int bid = blockIdx.x;  // 0..79 -> E2[p*10+k]; 80..89 -> Emean row + E2m[k]
  int lane = threadIdx.x;  // block = 64
  if (bid < 80) {
    const float* src = E + (size_t)bid * DIM;
    float s = 0.f;
    for (int i = lane; i < DIM; i += 64) {
      float v = src[i];
      s = fmaf(v, v, s);
    }
#pragma unroll
    for (int m = 1; m < 64; m <<= 1) s += __shfl_xor(s, m, 64);
    if (lane == 0) E2[bid] = s;
  } else {
    int k = bid - 80;
    float acc = 0.f;
    for (int i = lane; i < DIM; i += 64) {
      float s = 0.f;
#pragma unroll
      for (int p = 0; p < NP; ++p) s += E[p * NK * DIM + k * DIM + i];
      s *= 0.125f;
      Emean[k * DIM + i] = s;
      acc = fmaf(s, s, acc);
    }
#pragma unroll
    for (int m = 1; m < 64; m <<= 1) acc += __shfl_xor(acc, m, 64);
    if (lane == 0) E2m[k] = acc;
  }
}

// ---------------- etilde + Eimg pack: Et=W2^T E (fp16-split padded image), c=b2·E ----------------

__global__ __launch_bounds__(512) void etilde_kernel(const float* __restrict__ W2,
                                                     const float* __restrict__ b2,
                                                     const float* __restrict__ E,
                                                     f16* __restrict__ EimgH,
                                                     f16* __restrict__ EimgL,
                                                     float* __restrict__ c_) {
  const int p = blockIdx.x / NK, k = blockIdx.x % NK;
  const int h = threadIdx.x;  // 512 threads
  __shared__ float Er[512];
  __shared__ float red[8];
  Er[h] = E[((size_t)p * NK + k) * DIM + h];
  __syncthreads();
  const float* Wp = W2 + (size_t)p * DIM * DIM;
  float s = 0.f;
#pragma unroll 8
  for (int d = 0; d < DIM; ++d) s = fmaf(Wp[(size_t)d * DIM + h], Er[d], s);
  int ei = p * 8320 + k * 520 + h;
  f16 hi = (f16)s;
  EimgH[ei] = hi;
  EimgL[ei] = (f16)(s - (float)hi);
  if (h < 8) {
    int pi = p * 8320 + k * 520 + 512 + h;
    EimgH[pi] = (f16)0.f;
    EimgL[pi] = (f16)0.f;
  }
  if (k == 0) {
    for (int j = h; j < 6 * 520; j += 512) {
      int pi = p * 8320 + 10 * 520 + j;
      EimgH[pi] = (f16)0.f;
      EimgL[pi] = (f16)0.f;
    }
  }
  float t = b2[p * DIM + h] * Er[h];
#pragma unroll
  for (int m = 1; m < 64; m <<= 1) t += __shfl_xor(t, m, 64);
  if ((h & 63) == 0) red[h >> 6] = t;
  __syncthreads();
  if (h == 0) {
    float cc = 0.f;
#pragma unroll
    for (int i = 0; i < 8; ++i) cc += red[i];
    c_[p * NK + k] = cc;
  }
}

// ---------------- m97-style 128x128 GEMM-BT (16x16x32 MFMA — round-7 proven) ----------------

template <int EPI, int NBN, int NPROD, int GRP>
__global__ __launch_bounds__(256) void gemmA(
    const f16* __restrict__ Ah_, const f16* __restrict__ Al_, int lda, int apitch,
    const f16* __restrict__ Bh_, const f16* __restrict__ Bl_, int bpitch,
    const float* __restrict__ bias_, int bias_pitch,
    f16* __restrict__ Oh, f16* __restrict__ Ol, int ldo,
    float* __restrict__ part2) {
  __shared__ f16 smem[32768];  // 64 KB: 2 buf x [A 8192 | B 8192]
  const int tid = threadIdx.x;
  const int lane = tid & 63;
  const int wave = tid >> 6;
  const int wr = wave >> 1, wc = wave & 1;
  const int p = blockIdx.z;

  const int q8 = gridDim.x >> 3;
  const int bid = blockIdx.x;
  const int swz = (bid & 7) * q8 + (bid >> 3);
  const int band = swz / (GRP * NBN);
  const int r_ = swz % (GRP * NBN);
  const int bm = band * GRP + (r_ % GRP);
  const int bn = r_ / GRP;
  const int m0 = bm * 128, n0 = bn * 128;

  const f16* Ahp = Ah_ + (size_t)p * apitch;
  const f16* Alp = Al_ + (size_t)p * apitch;
  const f16* Bhp = Bh_ + (size_t)p * bpitch;
  const f16* Blp = Bl_ + (size_t)p * bpitch;

  const int NT = (NPROD == 3) ? 24 : 8;

  f32x4 acc[4][4] = {};

  auto stage = [&](int buf, int t) {
    const f16* As;
    const f16* Bs;
    int k0;
    if (NPROD == 3) {
      int pr = t % 3;  // 0:(Ah,Bh) 1:(Ah,Bl) 2:(Al,Bh)
      As = (pr == 2) ? Alp : Ahp;
      Bs = (pr == 1) ? Blp : Bhp;
      k0 = (t / 3) * 64;
    } else {
      As = Ahp;
      Bs = Bhp;
      k0 = t * 64;
    }
    f16* sA = smem + buf * 16384;
    f16* sB = sA + 8192;
#pragma unroll
    for (int j = 0; j < 4; ++j) {
      int r = j * 32 + (tid >> 3);
      int c = ((tid & 7) ^ (r & 7)) * 8;  // pre-swizzled source col
      gload_lds16(As + (size_t)(m0 + r) * lda + k0 + c, sA + j * 2048 + tid * 8);
      gload_lds16(Bs + (size_t)(n0 + r) * 512 + k0 + c, sB + j * 2048 + tid * 8);
    }
  };

  stage(0, 0);
  __syncthreads();

  const int g = lane >> 4, rl = lane & 15;

  for (int s = 0; s < NT; ++s) {
    int nx = s + 1;
    if (nx < NT) stage(nx & 1, nx);
    const char* sA = (const char*)(smem + (s & 1) * 16384);
    const char* sB = sA + 16384;  // bytes
    f16x8 af[4][2], bf[4][2];
#pragma unroll
    for (int i = 0; i < 4; ++i) {
      int ra = wr * 64 + i * 16 + rl;
      int rb = wc * 64 + i * 16 + rl;
#pragma unroll
      for (int kk = 0; kk < 2; ++kk) {
        int cb = kk * 64 + g * 16;
        af[i][kk] = *(const f16x8*)(sA + ra * 128 + (cb ^ ((ra & 7) << 4)));
        bf[i][kk] = *(const f16x8*)(sB + rb * 128 + (cb ^ ((rb & 7) << 4)));
      }
    }
#pragma unroll
    for (int i = 0; i < 4; ++i)
#pragma unroll
      for (int jn = 0; jn < 4; ++jn)
#pragma unroll
        for (int kk = 0; kk < 2; ++kk)
          acc[i][jn] = __builtin_amdgcn_mfma_f32_16x16x32_f16(af[i][kk], bf[jn][kk], acc[i][jn], 0, 0, 0);
    __syncthreads();
  }

  if (EPI == 0) {
#pragma unroll
    for (int jn = 0; jn < 4; ++jn) {
      int cg = n0 + wc * 64 + jn * 16 + rl;
      float bv = bias_[cg];
#pragma unroll
      for (int i = 0; i < 4; ++i) {
        int r0 = m0 + wr * 64 + i * 16 + g * 4;
#pragma unroll
        for (int r = 0; r < 4; ++r) {
          float z = acc[i][jn][r] + bv;
          z = fmaxf(z, 0.f);
          f16 h = (f16)z;
          size_t off = (size_t)(r0 + r) * ldo + cg;
          Oh[off] = h;
          Ol[off] = (f16)(z - (float)h);
        }
      }
    }
  } else {
    const float* bp = bias_ + (size_t)p * bias_pitch;
    float bvals[4];
#pragma unroll
    for (int jn = 0; jn < 4; ++jn) bvals[jn] = bp[n0 + wc * 64 + jn * 16 + rl];
    const int ch = bn * 2 + wc;  // 0..7 (NBN=4)
    float* pb = part2 + (size_t)(p * 8 + ch) * B_ROWS;
#pragma unroll
    for (int i = 0; i < 4; ++i) {
#pragma unroll
      for (int r = 0; r < 4; ++r) {
        float q = 0.f;
#pragma unroll
        for (int jn = 0; jn < 4; ++jn) {
          float z = acc[i][jn][r] + bvals[jn];
          q = fmaf(z, z, q);
        }
#pragma unroll
        for (int m = 1; m < 16; m <<= 1) q += __shfl_xor(q, m, 64);
        if (rl == 0) pb[m0 + wr * 64 + i * 16 + g * 4 + r] = q;
      }
    }
  }
}

// ---------------- dots via skinny MFMA, double-buffered 64-row tiles ----------------
// g[p][b][k] = h[b]·Et[p][k] + c[p][k]; writes into the dist output region.

__global__ __launch_bounds__(256) void dots_mfma(const f16* __restrict__ Hh,
                                                 const f16* __restrict__ Hl,
                                                 const f16* __restrict__ EimgH,
                                                 const f16* __restrict__ EimgL,
                                                 const float* __restrict__ c_,
                                                 float* __restrict__ gout) {
  __shared__ f16 sH[2][4096];     // 64x64 swizzled tiles
  __shared__ f16 sL[2][4096];
  __shared__ f16 sEh[16 * 520];   // padded rows: 1040 B stride
  __shared__ f16 sEl[16 * 520];
  const int tid = threadIdx.x;
  const int lane = tid & 63, wave = tid >> 6;
  const int p = blockIdx.y;
  const int r0 = blockIdx.x * 64;
  {
    const uint32_t* ih = (const uint32_t*)(EimgH + (size_t)p * 16 * 520);
    const uint32_t* il = (const uint32_t*)(EimgL + (size_t)p * 16 * 520);
    uint32_t* oh = (uint32_t*)sEh;
    uint32_t* ol = (uint32_t*)sEl;
    for (int i = tid; i < 16 * 520 / 2; i += 256) {
      oh[i] = ih[i];
      ol[i] = il[i];
    }
  }
  const int gq = lane >> 4, rl = lane & 15;

  auto stageT = [&](int buf, int t) {
#pragma unroll
    for (int rnd = 0; rnd < 2; ++rnd) {
      int w = rnd * 256 + tid;
      int r = w >> 3;
      int c = ((w & 7) ^ (r & 7)) * 8;  // pre-swizzled source col
      gload_lds16(Hh + (size_t)(r0 + r) * 4096 + p * DIM + t * 64 + c, &sH[buf][(size_t)w * 8]);
      gload_lds16(Hl + (size_t)(r0 + r) * 4096 + p * DIM + t * 64 + c, &sL[buf][(size_t)w * 8]);
    }
  };

  f32x4 acc = {};
  stageT(0, 0);
  __syncthreads();  // E copy + tile0 visible

  for (int t = 0; t < 8; ++t) {
    if (t < 7) stageT((t + 1) & 1, t + 1);
    const char* bh = (const char*)sH[t & 1];
    const char* bl = (const char*)sL[t & 1];
    const int ra = wave * 16 + rl;
    f16x8 ah[2], al[2], beh[2], bel[2];
#pragma unroll
    for (int kk = 0; kk < 2; ++kk) {
      int cb = kk * 64 + gq * 16;
      ah[kk] = *(const f16x8*)(bh + ra * 128 + (cb ^ ((ra & 7) << 4)));
      al[kk] = *(const f16x8*)(bl + ra * 128 + (cb ^ ((ra & 7) << 4)));
      int ce = t * 128 + kk * 64 + gq * 16;
      beh[kk] = *(const f16x8*)((const char*)sEh + rl * 1040 + ce);
      bel[kk] = *(const f16x8*)((const char*)sEl + rl * 1040 + ce);
    }
#pragma unroll
    for (int kk = 0; kk < 2; ++kk) {
      acc = __builtin_amdgcn_mfma_f32_16x16x32_f16(ah[kk], beh[kk], acc, 0, 0, 0);
      acc = __builtin_amdgcn_mfma_f32_16x16x32_f16(ah[kk], bel[kk], acc, 0, 0, 0);
      acc = __builtin_amdgcn_mfma_f32_16x16x32_f16(al[kk], beh[kk], acc, 0, 0, 0);
    }
    __syncthreads();
  }
  if (rl < NK) {
    float cv = c_[p * NK + rl];
#pragma unroll
    for (int r = 0; r < 4; ++r) {
      int row = r0 + wave * 16 + gq * 4 + r;
      gout[((size_t)p * B_ROWS + row) * NK + rl] = acc[r] + cv;
    }
  }
}

// ---------------- final: dist in-place, argmin, vq_z, loss, changed, avz (fused bcast) ----------------
// avz hole (k==8 && b<4096) holds part2 scratch; filled by bcast_rest afterwards.

__global__ __launch_bounds__(256) void final_kernel(
    const float* __restrict__ X, const float* __restrict__ part2,
    float* __restrict__ gdist, const float* __restrict__ E2,
    const float* __restrict__ Emean, const float* __restrict__ E2m,
    const int* __restrict__ label, float* __restrict__ vq_z,
    float* __restrict__ avz, float* __restrict__ loss, float* __restrict__ changed) {
  __shared__ float Em[NK * DIM];
  __shared__ float e2s[NK];
  const int tid = threadIdx.x;
  for (int i = tid; i < NK * DIM; i += 256) Em[i] = Emean[i];
  if (tid < NK) e2s[tid] = E2m[tid];
  __syncthreads();

  const int b0 = blockIdx.x * 16;
  {
    const float4* Em4 = (const float4*)Em;
    float4* avz4 = (float4*)avz;
    if (blockIdx.x < 256) {
      for (int it = 0; it < 80; ++it) {
        int idx = it * 256 + tid;
        int d4 = idx & 127, row = (idx >> 7) & 15, k = idx >> 11;
        if (k == 8) continue;  // hole: part2 scratch
        avz4[(((size_t)k * B_ROWS + b0 + row) << 7) + d4] = Em4[k * 128 + d4];
      }
    } else {
      for (int it = 0; it < 80; ++it) {
        int idx = it * 256 + tid;
        int d4 = idx & 127, row = (idx >> 7) & 15, k = idx >> 11;
        avz4[(((size_t)k * B_ROWS + b0 + row) << 7) + d4] = Em4[k * 128 + d4];
      }
    }
  }

  const int lane = tid & 63, wave = tid >> 6;
  const int pl = lane & 7, kh = lane >> 3;
  for (int rr = 0; rr < 4; ++rr) {
    int b = b0 + wave * 4 + rr;
    float zq = part2[(size_t)(pl * 8 + kh) * B_ROWS + b];
    zq += __shfl_xor(zq, 8, 64);
    zq += __shfl_xor(zq, 16, 64);
    zq += __shfl_xor(zq, 32, 64);
    float g0 = gdist[((size_t)pl * B_ROWS + b) * NK + kh];
    float g1 = (lane < 16) ? gdist[((size_t)pl * B_ROWS + b) * NK + 8 + kh] : 0.f;
    float dv0 = zq + E2[pl * NK + kh] - 2.f * g0;
    float dv1 = zq + E2[pl * NK + 8 + kh] - 2.f * g1;
    gdist[((size_t)pl * B_ROWS + b) * NK + kh] = dv0;
    if (lane < 16) gdist[((size_t)pl * B_ROWS + b) * NK + 8 + kh] = dv1;
    float v0 = dv0, v1 = (lane < 16) ? dv1 : 0.f;
#pragma unroll
    for (int m = 1; m < 8; m <<= 1) {
      v0 += __shfl_xor(v0, m, 64);
      v1 += __shfl_xor(v1, m, 64);
    }
    float a[NK];
#pragma unroll
    for (int k = 0; k < 8; ++k) a[k] = __shfl(v0, k * 8, 64);
    a[8] = __shfl(v1, 0, 64);
    a[9] = __shfl(v1, 8, 64);
    int idx = 0;
    float mn = a[0];
#pragma unroll
    for (int k = 1; k < NK; ++k) {
      if (a[k] < mn) { mn = a[k]; idx = k; }
    }
    const float* xr = X + (size_t)b * DIM;
    float sx = 0.f, dx[NK] = {};
#pragma unroll
    for (int j = 0; j < 8; ++j) {
      float x = xr[j * 64 + lane];
      sx = fmaf(x, x, sx);
#pragma unroll
      for (int k = 0; k < NK; ++k) dx[k] = fmaf(x, Em[k * DIM + j * 64 + lane], dx[k]);
    }
#pragma unroll
    for (int m = 1; m < 64; m <<= 1) {
      sx += __shfl_xor(sx, m, 64);
#pragma unroll
      for (int k = 0; k < NK; ++k) dx[k] += __shfl_xor(dx[k], m, 64);
    }
    if (lane == 0) {
#pragma unroll
      for (int k = 0; k < NK; ++k)
        loss[(size_t)k * B_ROWS + b] = 1.25f * (sx - 2.f * dx[k] + e2s[k]);
    }
    int lab = label[b];
#pragma unroll
    for (int j = 0; j < 8; ++j) {
      int c = j * 64 + lane;
      vq_z[(size_t)b * DIM + c] = Em[idx * DIM + c];
      changed[(size_t)b * DIM + c] = Em[lab * DIM + c];
    }
  }
}

// ---------------- bcast_rest: fill the avz hole (k=8, b<4096) ----------------

__global__ void bcast_rest(const float* __restrict__ Emean, float4* __restrict__ avz4) {
  const float4* Em4 = (const float4*)Emean;
  int tid = blockIdx.x * 256 + threadIdx.x;
  for (int it = 0; it < 32; ++it) {
    int idx = tid + it * 16384;  // 0 .. 524287
    int b = idx >> 7, d4 = idx & 127;
    avz4[((size_t)(8 * B_ROWS + b) << 7) + d4] = Em4[8 * 128 + d4];
  }
}

// ---------------- launch ----------------

extern "C" void kernel_launch(void* const* d_in, const int* in_sizes, int n_in,
                              void* d_out, int out_size, void* d_ws, size_t ws_size,
                              hipStream_t stream) {
  const float* X = (const float*)d_in[0];
  const float* W1 = (const float*)d_in[1];
  const float* b1 = (const float*)d_in[2];
  const float* W2 = (const float*)d_in[3];
  const float* b2 = (const float*)d_in[4];
  const float* E = (const float*)d_in[5];
  const int* lab = (const int*)d_in[6];
  float* out = (float*)d_out;

  // output layout (flat f32, return order)
  float* vq_z = out;                               // 16,777,216
  float* dist = out + 16777216;                    // 2,621,440
  float* avz = out + 16777216 + 2621440;           // 167,772,160
  float* loss = avz + 167772160;                   // 327,680
  float* chg = loss + 327680;                      // 16,777,216

  // scratch carved from output regions:
  f16* Xh = (f16*)vq_z;                       // 33.5 MB (consumed by GEMM1)
  f16* Xl = Xh + 16777216;
  f16* Hh = (f16*)avz;                        // 268 MB
  f16* Hl = Hh + 134217728;                   // 268 MB
  float* part2 = avz + 134217728;             // 8 MB = avz rows (k=8, b<4096) — the hole

  // small ws allocations (~13 MB)
  char* w = (char*)d_ws;
  f16* W1h = (f16*)w; w += 4194304;
  f16* W1l = (f16*)w; w += 4194304;
  f16* W2h = (f16*)w; w += 4194304;
  float* Emean = (float*)w; w += NK * DIM * 4;
  float* E2 = (float*)w; w += 512;
  float* E2m = (float*)w; w += 256;
  float* c_ = (float*)w; w += 512;
  f16* EimgH = (f16*)w; w += NP * 16 * 520 * 2;   // 133 KB
  f16* EimgL = (f16*)w; w += NP * 16 * 520 * 2;

  prep_split<<<1280, 256, 0, stream>>>((const float4*)X, (f16x4*)Xh, (f16x4*)Xl,
                                       (const float4*)W1, (f16x4*)W1h, (f16x4*)W1l,
                                       (const float4*)W2, (f16x4*)W2h);
  enorm2<<<90, 64, 0, stream>>>(E, Emean, E2, E2m);
  etilde_kernel<<<80, 512, 0, stream>>>(W2, b2, E, EimgH, EimgL, c_);

  // GEMM1: [32768x512] x [4096x512]^T -> Hh/Hl (relu + f16 split), 3 products
  gemmA<0, 32, 3, 8><<<dim3(8192, 1, 1), 256, 0, stream>>>(
      Xh, Xl, 512, 0, W1h, W1l, 0, b1, 0, Hh, Hl, 4096, nullptr);
  // GEMM2: per-p [32768x512] x [512x512]^T, 1 product -> zsq partials
  gemmA<1, 4, 1, 1><<<dim3(1024, 1, NP), 256, 0, stream>>>(
      Hh, Hh, 4096, 512, W2h, W2h, 262144, b2, 512, nullptr, nullptr, 0, part2);

  // dots: g -> dist region (in-place consumed by final)
  dots_mfma<<<dim3(512, NP), 256, 0, stream>>>(Hh, Hl, EimgH, EimgL, c_, dist);
  final_kernel<<<2048, 256, 0, stream>>>(X, part2, dist, E2, Emean, E2m, lab,
                                         vq_z, avz, loss, chg);
  bcast_rest<<<64, 256, 0, stream>>>(Emean, (float4*)avz);
}

// Round 10
// 1065.471 us; speedup vs baseline: 1.1033x; 1.0422x over previous
//
#include <hip/hip_runtime.h>
#include <stdint.h>

typedef _Float16 f16;
typedef _Float16 f16x4 __attribute__((ext_vector_type(4)));
typedef _Float16 f16x8 __attribute__((ext_vector_type(8)));
typedef float f32x4 __attribute__((ext_vector_type(4)));

#define B_ROWS 32768
#define DIM 512
#define NP 8
#define NK 10

typedef __attribute__((address_space(3))) unsigned int lds_u32;
typedef __attribute__((address_space(1))) const unsigned int gbl_u32;

__device__ __forceinline__ void gload_lds16(const void* g, void* l) {
  __builtin_amdgcn_global_load_lds((gbl_u32*)(uintptr_t)g, (lds_u32*)(uintptr_t)l, 16, 0, 0);
}

// ---------------- prep: vectorized combined split (X hi/lo, W1 hi/lo, W2 hi) ----------------

__global__ void prep_split(const float4* __restrict__ X4, f16x4* __restrict__ Xh4,
                           f16x4* __restrict__ Xl4, const float4* __restrict__ W14,
                           f16x4* __restrict__ W1h4, f16x4* __restrict__ W1l4,
                           const float4* __restrict__ W24, f16x4* __restrict__ W2h4) {
  int bid = blockIdx.x, tid = threadIdx.x;
  if (bid < 1024) {
    for (int i = bid * 256 + tid; i < 4194304; i += 1024 * 256) {
      float4 v = X4[i];
      f16x4 h = {(f16)v.x, (f16)v.y, (f16)v.z, (f16)v.w};
      f16x4 l = {(f16)(v.x - (float)h[0]), (f16)(v.y - (float)h[1]),
                 (f16)(v.z - (float)h[2]), (f16)(v.w - (float)h[3])};
      Xh4[i] = h;
      Xl4[i] = l;
    }
  } else if (bid < 1152) {
    for (int i = (bid - 1024) * 256 + tid; i < 524288; i += 128 * 256) {
      float4 v = W14[i];
      f16x4 h = {(f16)v.x, (f16)v.y, (f16)v.z, (f16)v.w};
      f16x4 l = {(f16)(v.x - (float)h[0]), (f16)(v.y - (float)h[1]),
                 (f16)(v.z - (float)h[2]), (f16)(v.w - (float)h[3])};
      W1h4[i] = h;
      W1l4[i] = l;
    }
  } else {
    for (int i = (bid - 1152) * 256 + tid; i < 524288; i += 128 * 256) {
      float4 v = W24[i];
      f16x4 h = {(f16)v.x, (f16)v.y, (f16)v.z, (f16)v.w};
      W2h4[i] = h;
    }
  }
}

// ---------------- enorm2: E2 rows + Emean rows + E2m ----------------

__global__ void enorm2(const float* __restrict__ E, float* __restrict__ Emean,
                       float* __restrict__ E2, float* __restrict__ E2m) {
  int bid = blockIdx.x;  // 0..79 -> E2[p*10+k]; 80..89 -> Emean row + E2m[k]
  int lane = threadIdx.x;  // block = 64
  if (bid < 80) {
    const float* src = E + (size_t)bid * DIM;
    float s = 0.f;
    for (int i = lane; i < DIM; i += 64) {
      float v = src[i];
      s = fmaf(v, v, s);
    }
#pragma unroll
    for (int m = 1; m < 64; m <<= 1) s += __shfl_xor(s, m, 64);
    if (lane == 0) E2[bid] = s;
  } else {
    int k = bid - 80;
    float acc = 0.f;
    for (int i = lane; i < DIM; i += 64) {
      float s = 0.f;
#pragma unroll
      for (int p = 0; p < NP; ++p) s += E[p * NK * DIM + k * DIM + i];
      s *= 0.125f;
      Emean[k * DIM + i] = s;
      acc = fmaf(s, s, acc);
    }
#pragma unroll
    for (int m = 1; m < 64; m <<= 1) acc += __shfl_xor(acc, m, 64);
    if (lane == 0) E2m[k] = acc;
  }
}

// ---------------- etilde + Eimg pack: Et=W2^T E (fp16-split padded image), c=b2·E ----------------

__global__ __launch_bounds__(512) void etilde_kernel(const float* __restrict__ W2,
                                                     const float* __restrict__ b2,
                                                     const float* __restrict__ E,
                                                     f16* __restrict__ EimgH,
                                                     f16* __restrict__ EimgL,
                                                     float* __restrict__ c_) {
  const int p = blockIdx.x / NK, k = blockIdx.x % NK;
  const int h = threadIdx.x;  // 512 threads
  __shared__ float Er[512];
  __shared__ float red[8];
  Er[h] = E[((size_t)p * NK + k) * DIM + h];
  __syncthreads();
  const float* Wp = W2 + (size_t)p * DIM * DIM;
  float s = 0.f;
#pragma unroll 8
  for (int d = 0; d < DIM; ++d) s = fmaf(Wp[(size_t)d * DIM + h], Er[d], s);
  int ei = p * 8320 + k * 520 + h;
  f16 hi = (f16)s;
  EimgH[ei] = hi;
  EimgL[ei] = (f16)(s - (float)hi);
  if (h < 8) {
    int pi = p * 8320 + k * 520 + 512 + h;
    EimgH[pi] = (f16)0.f;
    EimgL[pi] = (f16)0.f;
  }
  if (k == 0) {
    for (int j = h; j < 6 * 520; j += 512) {
      int pi = p * 8320 + 10 * 520 + j;
      EimgH[pi] = (f16)0.f;
      EimgL[pi] = (f16)0.f;
    }
  }
  float t = b2[p * DIM + h] * Er[h];
#pragma unroll
  for (int m = 1; m < 64; m <<= 1) t += __shfl_xor(t, m, 64);
  if ((h & 63) == 0) red[h >> 6] = t;
  __syncthreads();
  if (h == 0) {
    float cc = 0.f;
#pragma unroll
    for (int i = 0; i < 8; ++i) cc += red[i];
    c_[p * NK + k] = cc;
  }
}

// ---------------- m97-style 128x128 GEMM-BT (GEMM1, EPI0 — round-7 proven) ----------------

template <int EPI, int NBN, int NPROD, int GRP>
__global__ __launch_bounds__(256) void gemmA(
    const f16* __restrict__ Ah_, const f16* __restrict__ Al_, int lda, int apitch,
    const f16* __restrict__ Bh_, const f16* __restrict__ Bl_, int bpitch,
    const float* __restrict__ bias_, int bias_pitch,
    f16* __restrict__ Oh, f16* __restrict__ Ol, int ldo,
    float* __restrict__ part2) {
  __shared__ f16 smem[32768];  // 64 KB: 2 buf x [A 8192 | B 8192]
  const int tid = threadIdx.x;
  const int lane = tid & 63;
  const int wave = tid >> 6;
  const int wr = wave >> 1, wc = wave & 1;
  const int p = blockIdx.z;

  const int q8 = gridDim.x >> 3;
  const int bid = blockIdx.x;
  const int swz = (bid & 7) * q8 + (bid >> 3);
  const int band = swz / (GRP * NBN);
  const int r_ = swz % (GRP * NBN);
  const int bm = band * GRP + (r_ % GRP);
  const int bn = r_ / GRP;
  const int m0 = bm * 128, n0 = bn * 128;

  const f16* Ahp = Ah_ + (size_t)p * apitch;
  const f16* Alp = Al_ + (size_t)p * apitch;
  const f16* Bhp = Bh_ + (size_t)p * bpitch;
  const f16* Blp = Bl_ + (size_t)p * bpitch;

  const int NT = (NPROD == 3) ? 24 : 8;

  f32x4 acc[4][4] = {};

  auto stage = [&](int buf, int t) {
    const f16* As;
    const f16* Bs;
    int k0;
    if (NPROD == 3) {
      int pr = t % 3;  // 0:(Ah,Bh) 1:(Ah,Bl) 2:(Al,Bh)
      As = (pr == 2) ? Alp : Ahp;
      Bs = (pr == 1) ? Blp : Bhp;
      k0 = (t / 3) * 64;
    } else {
      As = Ahp;
      Bs = Bhp;
      k0 = t * 64;
    }
    f16* sA = smem + buf * 16384;
    f16* sB = sA + 8192;
#pragma unroll
    for (int j = 0; j < 4; ++j) {
      int r = j * 32 + (tid >> 3);
      int c = ((tid & 7) ^ (r & 7)) * 8;  // pre-swizzled source col
      gload_lds16(As + (size_t)(m0 + r) * lda + k0 + c, sA + j * 2048 + tid * 8);
      gload_lds16(Bs + (size_t)(n0 + r) * 512 + k0 + c, sB + j * 2048 + tid * 8);
    }
  };

  stage(0, 0);
  __syncthreads();

  const int g = lane >> 4, rl = lane & 15;

  for (int s = 0; s < NT; ++s) {
    int nx = s + 1;
    if (nx < NT) stage(nx & 1, nx);
    const char* sA = (const char*)(smem + (s & 1) * 16384);
    const char* sB = sA + 16384;  // bytes
    f16x8 af[4][2], bf[4][2];
#pragma unroll
    for (int i = 0; i < 4; ++i) {
      int ra = wr * 64 + i * 16 + rl;
      int rb = wc * 64 + i * 16 + rl;
#pragma unroll
      for (int kk = 0; kk < 2; ++kk) {
        int cb = kk * 64 + g * 16;
        af[i][kk] = *(const f16x8*)(sA + ra * 128 + (cb ^ ((ra & 7) << 4)));
        bf[i][kk] = *(const f16x8*)(sB + rb * 128 + (cb ^ ((rb & 7) << 4)));
      }
    }
#pragma unroll
    for (int i = 0; i < 4; ++i)
#pragma unroll
      for (int jn = 0; jn < 4; ++jn)
#pragma unroll
        for (int kk = 0; kk < 2; ++kk)
          acc[i][jn] = __builtin_amdgcn_mfma_f32_16x16x32_f16(af[i][kk], bf[jn][kk], acc[i][jn], 0, 0, 0);
    __syncthreads();
  }

  if (EPI == 0) {
#pragma unroll
    for (int jn = 0; jn < 4; ++jn) {
      int cg = n0 + wc * 64 + jn * 16 + rl;
      float bv = bias_[cg];
#pragma unroll
      for (int i = 0; i < 4; ++i) {
        int r0 = m0 + wr * 64 + i * 16 + g * 4;
#pragma unroll
        for (int r = 0; r < 4; ++r) {
          float z = acc[i][jn][r] + bv;
          z = fmaxf(z, 0.f);
          f16 h = (f16)z;
          size_t off = (size_t)(r0 + r) * ldo + cg;
          Oh[off] = h;
          Ol[off] = (f16)(z - (float)h);
        }
      }
    }
  } else {
    const float* bp = bias_ + (size_t)p * bias_pitch;
    float bvals[4];
#pragma unroll
    for (int jn = 0; jn < 4; ++jn) bvals[jn] = bp[n0 + wc * 64 + jn * 16 + rl];
    const int ch = bn * 2 + wc;
    float* pb = part2 + (size_t)(p * 8 + ch) * B_ROWS;
#pragma unroll
    for (int i = 0; i < 4; ++i) {
#pragma unroll
      for (int r = 0; r < 4; ++r) {
        float q = 0.f;
#pragma unroll
        for (int jn = 0; jn < 4; ++jn) {
          float z = acc[i][jn][r] + bvals[jn];
          q = fmaf(z, z, q);
        }
#pragma unroll
        for (int m = 1; m < 16; m <<= 1) q += __shfl_xor(q, m, 64);
        if (rl == 0) pb[m0 + wr * 64 + i * 16 + g * 4 + r] = q;
      }
    }
  }
}

// ---------------- union: GEMM2 (x<1024) + dots (x>=1024), p = blockIdx.y ----------------
// Fused into ONE dispatch so the BW-bound dots blocks overlap the
// MFMA/structure-bound GEMM2 blocks (same-stream kernels cannot overlap).

__global__ __launch_bounds__(256) void g2d_union(
    const f16* __restrict__ Hh, const f16* __restrict__ Hl,
    const f16* __restrict__ W2h, const float* __restrict__ b2,
    const f16* __restrict__ EimgH, const f16* __restrict__ EimgL,
    const float* __restrict__ c_, float* __restrict__ part2,
    float* __restrict__ gout) {
  __shared__ char pool[66048];  // max(GEMM2 64K, dots 64.5K) -> 2 blocks/CU
  const int tid = threadIdx.x;
  const int p = blockIdx.y;

  if (blockIdx.x < 1024) {
    // ===== GEMM2 body: per-p [32768x512] x [512x512]^T, 1 product -> zsq partials
    f16* smem = (f16*)pool;
    const int lane = tid & 63, wave = tid >> 6;
    const int wr = wave >> 1, wc = wave & 1;
    const int bid = blockIdx.x;
    const int swz = (bid & 7) * 128 + (bid >> 3);  // q8 = 1024/8
    const int bm = swz >> 2, bn = swz & 3;         // GRP=1, NBN=4
    const int m0 = bm * 128, n0 = bn * 128;
    const f16* Ahp = Hh + (size_t)p * 512;
    const f16* Bhp = W2h + (size_t)p * 262144;

    f32x4 acc[4][4] = {};

    auto stage = [&](int buf, int t) {
      int k0 = t * 64;
      f16* sA = smem + buf * 16384;
      f16* sB = sA + 8192;
#pragma unroll
      for (int j = 0; j < 4; ++j) {
        int r = j * 32 + (tid >> 3);
        int c = ((tid & 7) ^ (r & 7)) * 8;
        gload_lds16(Ahp + (size_t)(m0 + r) * 4096 + k0 + c, sA + j * 2048 + tid * 8);
        gload_lds16(Bhp + (size_t)(n0 + r) * 512 + k0 + c, sB + j * 2048 + tid * 8);
      }
    };

    stage(0, 0);
    __syncthreads();
    const int g = lane >> 4, rl = lane & 15;
    for (int s = 0; s < 8; ++s) {
      if (s + 1 < 8) stage((s + 1) & 1, s + 1);
      const char* sA = (const char*)(smem + (s & 1) * 16384);
      const char* sB = sA + 16384;
      f16x8 af[4][2], bf[4][2];
#pragma unroll
      for (int i = 0; i < 4; ++i) {
        int ra = wr * 64 + i * 16 + rl;
        int rb = wc * 64 + i * 16 + rl;
#pragma unroll
        for (int kk = 0; kk < 2; ++kk) {
          int cb = kk * 64 + g * 16;
          af[i][kk] = *(const f16x8*)(sA + ra * 128 + (cb ^ ((ra & 7) << 4)));
          bf[i][kk] = *(const f16x8*)(sB + rb * 128 + (cb ^ ((rb & 7) << 4)));
        }
      }
#pragma unroll
      for (int i = 0; i < 4; ++i)
#pragma unroll
        for (int jn = 0; jn < 4; ++jn)
#pragma unroll
          for (int kk = 0; kk < 2; ++kk)
            acc[i][jn] = __builtin_amdgcn_mfma_f32_16x16x32_f16(af[i][kk], bf[jn][kk], acc[i][jn], 0, 0, 0);
      __syncthreads();
    }

    const float* bp = b2 + (size_t)p * 512;
    float bvals[4];
#pragma unroll
    for (int jn = 0; jn < 4; ++jn) bvals[jn] = bp[n0 + wc * 64 + jn * 16 + rl];
    const int ch = bn * 2 + wc;
    float* pb = part2 + (size_t)(p * 8 + ch) * B_ROWS;
#pragma unroll
    for (int i = 0; i < 4; ++i) {
#pragma unroll
      for (int r = 0; r < 4; ++r) {
        float q = 0.f;
#pragma unroll
        for (int jn = 0; jn < 4; ++jn) {
          float z = acc[i][jn][r] + bvals[jn];
          q = fmaf(z, z, q);
        }
#pragma unroll
        for (int m = 1; m < 16; m <<= 1) q += __shfl_xor(q, m, 64);
        if (rl == 0) pb[m0 + wr * 64 + i * 16 + g * 4 + r] = q;
      }
    }
  } else {
    // ===== dots body: g[p][b][k] = h[b]·Et[p][k] + c[p][k] -> gout (dist region)
    f16* sH = (f16*)pool;              // [2][4096]
    f16* sL = (f16*)(pool + 16384);    // [2][4096]
    f16* sEh = (f16*)(pool + 32768);   // [16*520]
    f16* sEl = (f16*)(pool + 49408);   // [16*520]
    const int lane = tid & 63, wave = tid >> 6;
    const int r0 = (blockIdx.x - 1024) * 64;
    {
      const uint32_t* ih = (const uint32_t*)(EimgH + (size_t)p * 16 * 520);
      const uint32_t* il = (const uint32_t*)(EimgL + (size_t)p * 16 * 520);
      uint32_t* oh = (uint32_t*)sEh;
      uint32_t* ol = (uint32_t*)sEl;
      for (int i = tid; i < 16 * 520 / 2; i += 256) {
        oh[i] = ih[i];
        ol[i] = il[i];
      }
    }
    const int gq = lane >> 4, rl = lane & 15;

    auto stageT = [&](int buf, int t) {
#pragma unroll
      for (int rnd = 0; rnd < 2; ++rnd) {
        int w = rnd * 256 + tid;
        int r = w >> 3;
        int c = ((w & 7) ^ (r & 7)) * 8;
        gload_lds16(Hh + (size_t)(r0 + r) * 4096 + p * DIM + t * 64 + c,
                    sH + buf * 4096 + (size_t)w * 8);
        gload_lds16(Hl + (size_t)(r0 + r) * 4096 + p * DIM + t * 64 + c,
                    sL + buf * 4096 + (size_t)w * 8);
      }
    };

    f32x4 acc = {};
    stageT(0, 0);
    __syncthreads();  // E copy + tile0 visible

    for (int t = 0; t < 8; ++t) {
      if (t < 7) stageT((t + 1) & 1, t + 1);
      const char* bh = (const char*)(sH + (t & 1) * 4096);
      const char* bl = (const char*)(sL + (t & 1) * 4096);
      const int ra = wave * 16 + rl;
      f16x8 ah[2], al[2], beh[2], bel[2];
#pragma unroll
      for (int kk = 0; kk < 2; ++kk) {
        int cb = kk * 64 + gq * 16;
        ah[kk] = *(const f16x8*)(bh + ra * 128 + (cb ^ ((ra & 7) << 4)));
        al[kk] = *(const f16x8*)(bl + ra * 128 + (cb ^ ((ra & 7) << 4)));
        int ce = t * 128 + kk * 64 + gq * 16;
        beh[kk] = *(const f16x8*)((const char*)sEh + rl * 1040 + ce);
        bel[kk] = *(const f16x8*)((const char*)sEl + rl * 1040 + ce);
      }
#pragma unroll
      for (int kk = 0; kk < 2; ++kk) {
        acc = __builtin_amdgcn_mfma_f32_16x16x32_f16(ah[kk], beh[kk], acc, 0, 0, 0);
        acc = __builtin_amdgcn_mfma_f32_16x16x32_f16(ah[kk], bel[kk], acc, 0, 0, 0);
        acc = __builtin_amdgcn_mfma_f32_16x16x32_f16(al[kk], beh[kk], acc, 0, 0, 0);
      }
      __syncthreads();
    }
    if (rl < NK) {
      float cv = c_[p * NK + rl];
#pragma unroll
      for (int r = 0; r < 4; ++r) {
        int row = r0 + wave * 16 + gq * 4 + r;
        gout[((size_t)p * B_ROWS + row) * NK + rl] = acc[r] + cv;
      }
    }
  }
}

// ---------------- final: dist in-place, argmin, vq_z, loss, changed, avz (fused bcast) ----------------
// avz hole (k==8 && b<4096) holds part2 scratch; filled by bcast_rest afterwards.

__global__ __launch_bounds__(256) void final_kernel(
    const float* __restrict__ X, const float* __restrict__ part2,
    float* __restrict__ gdist, const float* __restrict__ E2,
    const float* __restrict__ Emean, const float* __restrict__ E2m,
    const int* __restrict__ label, float* __restrict__ vq_z,
    float* __restrict__ avz, float* __restrict__ loss, float* __restrict__ changed) {
  __shared__ float Em[NK * DIM];
  __shared__ float e2s[NK];
  const int tid = threadIdx.x;
  for (int i = tid; i < NK * DIM; i += 256) Em[i] = Emean[i];
  if (tid < NK) e2s[tid] = E2m[tid];
  __syncthreads();

  const int b0 = blockIdx.x * 16;
  {
    const float4* Em4 = (const float4*)Em;
    float4* avz4 = (float4*)avz;
    if (blockIdx.x < 256) {
      for (int it = 0; it < 80; ++it) {
        int idx = it * 256 + tid;
        int d4 = idx & 127, row = (idx >> 7) & 15, k = idx >> 11;
        if (k == 8) continue;  // hole: part2 scratch
        avz4[(((size_t)k * B_ROWS + b0 + row) << 7) + d4] = Em4[k * 128 + d4];
      }
    } else {
      for (int it = 0; it < 80; ++it) {
        int idx = it * 256 + tid;
        int d4 = idx & 127, row = (idx >> 7) & 15, k = idx >> 11;
        avz4[(((size_t)k * B_ROWS + b0 + row) << 7) + d4] = Em4[k * 128 + d4];
      }
    }
  }

  const int lane = tid & 63, wave = tid >> 6;
  const int pl = lane & 7, kh = lane >> 3;
  for (int rr = 0; rr < 4; ++rr) {
    int b = b0 + wave * 4 + rr;
    float zq = part2[(size_t)(pl * 8 + kh) * B_ROWS + b];
    zq += __shfl_xor(zq, 8, 64);
    zq += __shfl_xor(zq, 16, 64);
    zq += __shfl_xor(zq, 32, 64);
    float g0 = gdist[((size_t)pl * B_ROWS + b) * NK + kh];
    float g1 = (lane < 16) ? gdist[((size_t)pl * B_ROWS + b) * NK + 8 + kh] : 0.f;
    float dv0 = zq + E2[pl * NK + kh] - 2.f * g0;
    float dv1 = zq + E2[pl * NK + 8 + kh] - 2.f * g1;
    gdist[((size_t)pl * B_ROWS + b) * NK + kh] = dv0;
    if (lane < 16) gdist[((size_t)pl * B_ROWS + b) * NK + 8 + kh] = dv1;
    float v0 = dv0, v1 = (lane < 16) ? dv1 : 0.f;
#pragma unroll
    for (int m = 1; m < 8; m <<= 1) {
      v0 += __shfl_xor(v0, m, 64);
      v1 += __shfl_xor(v1, m, 64);
    }
    float a[NK];
#pragma unroll
    for (int k = 0; k < 8; ++k) a[k] = __shfl(v0, k * 8, 64);
    a[8] = __shfl(v1, 0, 64);
    a[9] = __shfl(v1, 8, 64);
    int idx = 0;
    float mn = a[0];
#pragma unroll
    for (int k = 1; k < NK; ++k) {
      if (a[k] < mn) { mn = a[k]; idx = k; }
    }
    const float* xr = X + (size_t)b * DIM;
    float sx = 0.f, dx[NK] = {};
#pragma unroll
    for (int j = 0; j < 8; ++j) {
      float x = xr[j * 64 + lane];
      sx = fmaf(x, x, sx);
#pragma unroll
      for (int k = 0; k < NK; ++k) dx[k] = fmaf(x, Em[k * DIM + j * 64 + lane], dx[k]);
    }
#pragma unroll
    for (int m = 1; m < 64; m <<= 1) {
      sx += __shfl_xor(sx, m, 64);
#pragma unroll
      for (int k = 0; k < NK; ++k) dx[k] += __shfl_xor(dx[k], m, 64);
    }
    if (lane == 0) {
#pragma unroll
      for (int k = 0; k < NK; ++k)
        loss[(size_t)k * B_ROWS + b] = 1.25f * (sx - 2.f * dx[k] + e2s[k]);
    }
    int lab = label[b];
#pragma unroll
    for (int j = 0; j < 8; ++j) {
      int c = j * 64 + lane;
      vq_z[(size_t)b * DIM + c] = Em[idx * DIM + c];
      changed[(size_t)b * DIM + c] = Em[lab * DIM + c];
    }
  }
}

// ---------------- bcast_rest: fill the avz hole (k=8, b<4096) ----------------

__global__ void bcast_rest(const float* __restrict__ Emean, float4* __restrict__ avz4) {
  const float4* Em4 = (const float4*)Emean;
  int tid = blockIdx.x * 256 + threadIdx.x;
  for (int it = 0; it < 32; ++it) {
    int idx = tid + it * 16384;  // 0 .. 524287
    int b = idx >> 7, d4 = idx & 127;
    avz4[((size_t)(8 * B_ROWS + b) << 7) + d4] = Em4[8 * 128 + d4];
  }
}

// ---------------- launch ----------------

extern "C" void kernel_launch(void* const* d_in, const int* in_sizes, int n_in,
                              void* d_out, int out_size, void* d_ws, size_t ws_size,
                              hipStream_t stream) {
  const float* X = (const float*)d_in[0];
  const float* W1 = (const float*)d_in[1];
  const float* b1 = (const float*)d_in[2];
  const float* W2 = (const float*)d_in[3];
  const float* b2 = (const float*)d_in[4];
  const float* E = (const float*)d_in[5];
  const int* lab = (const int*)d_in[6];
  float* out = (float*)d_out;

  // output layout (flat f32, return order)
  float* vq_z = out;                               // 16,777,216
  float* dist = out + 16777216;                    // 2,621,440
  float* avz = out + 16777216 + 2621440;           // 167,772,160
  float* loss = avz + 167772160;                   // 327,680
  float* chg = loss + 327680;                      // 16,777,216

  // scratch carved from output regions:
  f16* Xh = (f16*)vq_z;                       // 33.5 MB (consumed by GEMM1)
  f16* Xl = Xh + 16777216;
  f16* Hh = (f16*)avz;                        // 268 MB
  f16* Hl = Hh + 134217728;                   // 268 MB
  float* part2 = avz + 134217728;             // 8 MB = avz rows (k=8, b<4096) — the hole

  // small ws allocations (~13 MB)
  char* w = (char*)d_ws;
  f16* W1h = (f16*)w; w += 4194304;
  f16* W1l = (f16*)w; w += 4194304;
  f16* W2h = (f16*)w; w += 4194304;
  float* Emean = (float*)w; w += NK * DIM * 4;
  float* E2 = (float*)w; w += 512;
  float* E2m = (float*)w; w += 256;
  float* c_ = (float*)w; w += 512;
  f16* EimgH = (f16*)w; w += NP * 16 * 520 * 2;   // 133 KB
  f16* EimgL = (f16*)w; w += NP * 16 * 520 * 2;

  prep_split<<<1280, 256, 0, stream>>>((const float4*)X, (f16x4*)Xh, (f16x4*)Xl,
                                       (const float4*)W1, (f16x4*)W1h, (f16x4*)W1l,
                                       (const float4*)W2, (f16x4*)W2h);
  enorm2<<<90, 64, 0, stream>>>(E, Emean, E2, E2m);
  etilde_kernel<<<80, 512, 0, stream>>>(W2, b2, E, EimgH, EimgL, c_);

  // GEMM1: [32768x512] x [4096x512]^T -> Hh/Hl (relu + f16 split), 3 products
  gemmA<0, 32, 3, 8><<<dim3(8192, 1, 1), 256, 0, stream>>>(
      Xh, Xl, 512, 0, W1h, W1l, 0, b1, 0, Hh, Hl, 4096, nullptr);

  // union: GEMM2 (zsq partials) + dots (g -> dist region), overlapped in one dispatch
  g2d_union<<<dim3(1536, NP), 256, 0, stream>>>(Hh, Hl, W2h, b2, EimgH, EimgL, c_,
                                                part2, dist);

  final_kernel<<<2048, 256, 0, stream>>>(X, part2, dist, E2, Emean, E2m, lab,
                                         vq_z, avz, loss, chg);
  bcast_rest<<<64, 256, 0, stream>>>(Emean, (float4*)avz);
}